// Round 17
// baseline (498.440 us; speedup 1.0000x reference)
//
#include <hip/hip_runtime.h>
#include <cstdint>
#include <cstddef>

#define BN 8
#define NN 16384
#define DD 256
#define KK 16
#define NITER 5
#define EPSV 1e-8f
#define LOG256 5.545177444479562f
#define PSTR 260   // LDS row stride (words); 1040 B, 16B-aligned
#define TPB 8      // S-tiles per prep block
#define GG 64      // split-N partial count per batch (512 blocks -> 2/CU)

typedef float f32x4 __attribute__((ext_vector_type(4)));
typedef long  i64v;

__device__ __forceinline__ float frcp(float x){ return __builtin_amdgcn_rcpf(x); }
__device__ __forceinline__ float wmax(float v){
  #pragma unroll
  for (int m = 32; m >= 1; m >>= 1) v = fmaxf(v, __shfl_xor(v, m, 64));
  return v;
}
__device__ __forceinline__ float wsum(float v){
  #pragma unroll
  for (int m = 32; m >= 1; m >>= 1) v += __shfl_xor(v, m, 64);
  return v;
}
__device__ __forceinline__ uint32_t pk4_fp8(float a, float b, float c, float d){
  int w = __builtin_amdgcn_cvt_pk_fp8_f32(a, b, 0, false);
  w = __builtin_amdgcn_cvt_pk_fp8_f32(c, d, w, true);
  return (uint32_t)w;
}
__device__ __forceinline__ uint32_t f2bf(float f){
  uint32_t u = __float_as_uint(f);
  return (u + 0x7fffu + ((u >> 16) & 1u)) >> 16;
}
__device__ __forceinline__ uint32_t pk2bf(float a, float b){
  return f2bf(a) | (f2bf(b) << 16);
}
__device__ __forceinline__ float bf2f(uint32_t h){ return __uint_as_float(h << 16); }

// ---- prep: single-buffer, 4 blocks/CU (TLP hides stage latency) -----------
// pbf8/xbf8/invs layouts identical to r12-verified kernels.
__global__ __launch_bounds__(256, 4) void k_prep6(const float* __restrict__ x,
                                                  uint2* __restrict__ pbf8,
                                                  uint2* __restrict__ xbf8,
                                                  float* __restrict__ invs){
  __shared__ float xs[32 * PSTR];                  // 33.3 KB single buffer
  const int b = blockIdx.y;
  const int Sbase = blockIdx.x * TPB;
  const int tid = threadIdx.x;
  const int wave = tid >> 6, lane = tid & 63;
  const float* xb = x + (size_t)b * NN * DD;

  for (int it = 0; it < TPB; ++it){
    const int S = Sbase + it;
    // stage this tile: each wave its 8 rows, width-16 gload_lds
    #pragma unroll
    for (int r = 0; r < 8; ++r){
      int row = wave * 8 + r;
      const float* gp = xb + ((size_t)S * 32 + row) * DD + lane * 4;
      float* lp = &xs[row * PSTR];
      __builtin_amdgcn_global_load_lds(
          (const __attribute__((address_space(1))) unsigned int*)gp,
          (__attribute__((address_space(3))) unsigned int*)lp, 16, 0, 0);
    }
    asm volatile("s_waitcnt vmcnt(0)" ::: "memory");
    __builtin_amdgcn_sched_barrier(0);
    __syncthreads();                               // xs ready (all waves)

    // ---- row sums --------------------------------------------------------
    {
      int row = 8 * wave + (lane & 7);
      const float* pr = &xs[row * PSTR + (lane >> 3) * 32];
      float a = 0.f;
      #pragma unroll
      for (int i = 0; i < 8; ++i){
        float4 v = *(const float4*)&pr[4 * i];
        a += __expf(v.x) + __expf(v.y) + __expf(v.z) + __expf(v.w);
      }
      a += __shfl_xor(a, 8, 64);
      a += __shfl_xor(a, 16, 64);
      a += __shfl_xor(a, 32, 64);
      if (lane < 8) invs[(size_t)b * NN + S * 32 + 8 * wave + lane] = frcp(a);
    }
    // ---- pbf pack: 4 (c,s) tasks per wave --------------------------------
    #pragma unroll
    for (int i = 0; i < 4; ++i){
      int p = wave * 4 + i; int c = p >> 3, s = p & 7;
      int rho = lane & 15;
      int n = 8 * (rho >> 2) + 4 * c + (rho & 3);
      int d = 32 * s + 8 * (lane >> 4);
      float4 v0 = *(const float4*)&xs[n * PSTR + d];
      float4 v1 = *(const float4*)&xs[n * PSTR + d + 4];
      uint2 o;
      o.x = pk4_fp8(__expf(v0.x), __expf(v0.y), __expf(v0.z), __expf(v0.w));
      o.y = pk4_fp8(__expf(v1.x), __expf(v1.y), __expf(v1.z), __expf(v1.w));
      pbf8[(((size_t)b * 1024 + (size_t)S * 2 + c) * 8 + s) * 64 + lane] = o;
    }
    // ---- xbf pack: 4 dt tasks per wave -----------------------------------
    #pragma unroll
    for (int i = 0; i < 4; ++i){
      int dt = wave * 4 + i;
      int col = dt * 16 + (lane & 15);
      int g2 = lane >> 4;
      float v[8];
      #pragma unroll
      for (int j = 0; j < 8; ++j) v[j] = xs[(8 * g2 + j) * PSTR + col];
      uint2 o;
      o.x = pk4_fp8(v[0], v[1], v[2], v[3]);
      o.y = pk4_fp8(v[4], v[5], v[6], v[7]);
      xbf8[(((size_t)b * 512 + S) * 16 + dt) * 64 + lane] = o;
    }
    __syncthreads();                               // done reading xs
  }
}

// ---- init: lq residual fp8 B-frags + logpi (r12-verified) -----------------
__global__ __launch_bounds__(256) void k_init6(const float* __restrict__ slot_logits,
                                               const float* __restrict__ mix,
                                               uint8_t* __restrict__ lqf8,
                                               float* __restrict__ logpi){
  int w    = blockIdx.x * 4 + (threadIdx.x >> 6);   // b*K + k
  int lane = threadIdx.x & 63;
  int b = w >> 4, k = w & 15;
  const float4* sl = (const float4*)(slot_logits + (size_t)k * DD);
  float4 t = sl[lane];
  float m = wmax(fmaxf(fmaxf(t.x, t.y), fmaxf(t.z, t.w)));
  float s = wsum(__expf(t.x-m) + __expf(t.y-m) + __expf(t.z-m) + __expf(t.w-m));
  float L = m + __logf(s) - LOG256;
  int d0 = lane * 4;
  int ss = d0 >> 5;
  int l2 = (((d0 & 31) >> 3) << 4) + k;
  int jb = d0 & 7;
  uint32_t wv = pk4_fp8(t.x - L, t.y - L, t.z - L, t.w - L);
  *(uint32_t*)(lqf8 + ((((size_t)b * 8 + ss) * 64 + l2) * 8 + jb)) = wv;
  if (lane == 0) logpi[w] = __logf(mix[k] + EPSV);
}

// ---- threefry (VERIFIED) --------------------------------------------------
__device__ __forceinline__ uint32_t rotl32(uint32_t x, int r){ return (x << r) | (x >> (32 - r)); }
__device__ __forceinline__ void tf2x32(uint32_t k0, uint32_t k1, uint32_t c0, uint32_t c1,
                                       uint32_t& o0, uint32_t& o1){
  uint32_t ks0 = k0, ks1 = k1, ks2 = 0x1BD11BDAu ^ k0 ^ k1;
  uint32_t x0 = c0 + ks0, x1 = c1 + ks1;
  #define RND(r) { x0 += x1; x1 = rotl32(x1, r); x1 ^= x0; }
  RND(13) RND(15) RND(26) RND(6)   x0 += ks1; x1 += ks2 + 1u;
  RND(17) RND(29) RND(16) RND(24)  x0 += ks2; x1 += ks0 + 2u;
  RND(13) RND(15) RND(26) RND(6)   x0 += ks0; x1 += ks1 + 3u;
  RND(17) RND(29) RND(16) RND(24)  x0 += ks1; x1 += ks2 + 4u;
  RND(13) RND(15) RND(26) RND(6)   x0 += ks2; x1 += ks0 + 5u;
  #undef RND
  o0 = x0; o1 = x1;
}

// ---- reduce one (b,k) row: r15-verified reduce6 body ----------------------
__device__ __forceinline__ void dev_reduce_row(const uint16_t* __restrict__ pnumb,
    const float* __restrict__ ppi, uint8_t* __restrict__ lqf8,
    float* __restrict__ logpi, float* __restrict__ out,
    int b, int k, int lane, int dofinal){
  int w = b * KK + k;
  float4 sum = make_float4(0.f, 0.f, 0.f, 0.f);
  #pragma unroll 4
  for (int g = 0; g < GG; ++g){
    const uint2* p = (const uint2*)(pnumb +
        ((size_t)(b * GG + g) * KK + k) * DD + lane * 4);
    uint2 v = *p;
    sum.x += bf2f(v.x & 0xffffu); sum.y += bf2f(v.x >> 16);
    sum.z += bf2f(v.y & 0xffffu); sum.w += bf2f(v.y >> 16);
  }
  float ps = 0.f;
  for (int g = lane; g < GG; g += 64) ps += ppi[((size_t)b * GG + g) * KK + k];
  ps = wsum(ps);
  float inv = frcp(ps + EPSV);
  float4 th = make_float4(sum.x * inv, sum.y * inv, sum.z * inv, sum.w * inv);

  if (!dofinal){
    float m = wmax(fmaxf(fmaxf(th.x, th.y), fmaxf(th.z, th.w)));
    float s = wsum(__expf(th.x-m) + __expf(th.y-m) + __expf(th.z-m) + __expf(th.w-m));
    float L = m + __logf(s) - LOG256;
    int d0 = lane * 4;
    int ss = d0 >> 5;
    int l2 = (((d0 & 31) >> 3) << 4) + k;
    int jb = d0 & 7;
    uint32_t wv = pk4_fp8(th.x - L, th.y - L, th.z - L, th.w - L);
    *(uint32_t*)(lqf8 + ((((size_t)b * 8 + ss) * 64 + l2) * 8 + jb)) = wv;
    if (lane == 0) logpi[w] = __logf(ps * (1.0f / NN) + EPSV);
    return;
  }
  // final: gumbel + softmax -> out
  int i0 = w * DD + lane * 4;
  float gv[4];
  #pragma unroll
  for (int j = 0; j < 4; ++j){
    uint32_t i = (uint32_t)(i0 + j);
    uint32_t o0, o1;
    tf2x32(0u, 1u, 0u, i, o0, o1);
    uint32_t bits = o0 ^ o1;
    float f = __uint_as_float((bits >> 9) | 0x3f800000u) - 1.0f;
    const float TINY = 1.17549435e-38f;
    float u = fmaxf(f + TINY, TINY);
    gv[j] = -logf(-logf(u));
  }
  float4 y = make_float4(th.x + gv[0], th.y + gv[1], th.z + gv[2], th.w + gv[3]);
  float m = wmax(fmaxf(fmaxf(y.x, y.y), fmaxf(y.z, y.w)));
  float4 e = make_float4(__expf(y.x-m), __expf(y.y-m), __expf(y.z-m), __expf(y.w-m));
  float s = wsum(e.x + e.y + e.z + e.w);
  float invq = 1.0f / s;
  ((float4*)(out + (size_t)w * DD))[lane] =
      make_float4(e.x*invq, e.y*invq, e.z*invq, e.w*invq);
}

// ---- em iteration + last-block tail reduce --------------------------------
__global__ __launch_bounds__(256, 2) void k_em7(const uint2* __restrict__ pbf8,
                                                const uint2* __restrict__ xbf8,
                                                const uint2* __restrict__ lqf8v,
                                                const float* __restrict__ logpi,
                                                const float* __restrict__ invs,
                                                uint16_t* __restrict__ pnumb,
                                                float* __restrict__ ppi,
                                                uint8_t* __restrict__ lqf8,
                                                float* __restrict__ logpi_w,
                                                float* __restrict__ out,
                                                uint32_t* __restrict__ cnt,
                                                int dofinal){
  __shared__ float sred[KK * DD];
  __shared__ float spi2[16];
  __shared__ int amlast;
  const int b = blockIdx.y, g = blockIdx.x;          // g: 0..GG-1
  const int tid = threadIdx.x;
  const int wave = tid >> 6, lane = tid & 63;

  i64v lq8[8];
  {
    const uint2* p = lqf8v + (size_t)b * 8 * 64 + lane;
    #pragma unroll
    for (int s = 0; s < 8; ++s){ uint2 t = p[s * 64]; lq8[s] = *(i64v*)&t; }
  }
  const float lpik = logpi[b * KK + (lane & 15)];

  f32x4 acc[16];
  #pragma unroll
  for (int dt = 0; dt < 16; ++dt) acc[dt] = (f32x4){0.f, 0.f, 0.f, 0.f};
  float piacc = 0.f;

  const int S0 = (g * 4 + wave) * 2;                 // 2 supersteps per wave
  #pragma unroll
  for (int ssi = 0; ssi < 2; ++ssi){
    const int S = S0 + ssi;
    const uint2* pb = pbf8 + (((size_t)b * 1024 + (size_t)S * 2) * 8) * 64 + lane;
    const uint2* xr = xbf8 + (((size_t)b * 512 + S) * 16) * 64 + lane;
    uint2 pa[16];
    #pragma unroll
    for (int i = 0; i < 16; ++i) pa[i] = pb[(size_t)i * 64];
    float ivs[8];
    {
      const float* ib = invs + (size_t)b * NN + S * 32 + 8 * (lane >> 4);
      #pragma unroll
      for (int j = 0; j < 8; ++j) ivs[j] = ib[j];
    }
    float ga[8];
    #pragma unroll
    for (int c = 0; c < 2; ++c){
      f32x4 lc = (f32x4){0.f, 0.f, 0.f, 0.f};
      #pragma unroll
      for (int s = 0; s < 8; ++s){
        i64v a = *(i64v*)&pa[c * 8 + s];
        lc = __builtin_amdgcn_mfma_f32_16x16x32_fp8_fp8(a, lq8[s], lc, 0, 0, 0);
      }
      #pragma unroll
      for (int r2 = 0; r2 < 4; ++r2){
        float lg = fmaf(lc[r2], ivs[c * 4 + r2], lpik);
        float mx = lg;
        #pragma unroll
        for (int m = 1; m <= 8; m <<= 1) mx = fmaxf(mx, __shfl_xor(mx, m, 64));
        float e = __expf(lg - mx);
        float s2 = e;
        #pragma unroll
        for (int m = 1; m <= 8; m <<= 1) s2 += __shfl_xor(s2, m, 64);
        ga[c * 4 + r2] = e * frcp(s2);
      }
    }
    uint2 gp;
    gp.x = pk4_fp8(ga[0], ga[1], ga[2], ga[3]);
    gp.y = pk4_fp8(ga[4], ga[5], ga[6], ga[7]);
    piacc += __builtin_amdgcn_cvt_f32_fp8((int)gp.x, 0)
           + __builtin_amdgcn_cvt_f32_fp8((int)gp.x, 1)
           + __builtin_amdgcn_cvt_f32_fp8((int)gp.x, 2)
           + __builtin_amdgcn_cvt_f32_fp8((int)gp.x, 3)
           + __builtin_amdgcn_cvt_f32_fp8((int)gp.y, 0)
           + __builtin_amdgcn_cvt_f32_fp8((int)gp.y, 1)
           + __builtin_amdgcn_cvt_f32_fp8((int)gp.y, 2)
           + __builtin_amdgcn_cvt_f32_fp8((int)gp.y, 3);
    i64v gA = *(i64v*)&gp;
    #pragma unroll
    for (int dt = 0; dt < 16; ++dt){
      uint2 xv = xr[(size_t)dt * 64];
      acc[dt] = __builtin_amdgcn_mfma_f32_16x16x32_fp8_fp8(gA, *(i64v*)&xv,
                                                           acc[dt], 0, 0, 0);
    }
  }

  // cross-wave reduce (verified structure)
  float pk = piacc;
  pk += __shfl_xor(pk, 16, 64);
  pk += __shfl_xor(pk, 32, 64);
  __syncthreads();
  if (wave == 0){
    #pragma unroll
    for (int dt = 0; dt < 16; ++dt)
      #pragma unroll
      for (int r2 = 0; r2 < 4; ++r2)
        sred[(4 * (lane >> 4) + r2) * DD + dt * 16 + (lane & 15)] = acc[dt][r2];
    if (lane < 16) spi2[lane] = pk;
  }
  __syncthreads();
  for (int w = 1; w < 4; ++w){
    if (wave == w){
      #pragma unroll
      for (int dt = 0; dt < 16; ++dt)
        #pragma unroll
        for (int r2 = 0; r2 < 4; ++r2)
          sred[(4 * (lane >> 4) + r2) * DD + dt * 16 + (lane & 15)] += acc[dt][r2];
      if (lane < 16) spi2[lane] += pk;
    }
    __syncthreads();
  }
  uint32_t* dst = (uint32_t*)(pnumb + (size_t)(b * GG + g) * KK * DD);
  #pragma unroll
  for (int j = 0; j < 8; ++j){
    float a = sred[tid * 2 + j * 512];
    float c = sred[tid * 2 + 1 + j * 512];
    dst[tid + j * 256] = pk2bf(a, c);
  }
  if (tid < 16) ppi[(size_t)(b * GG + g) * KK + tid] = spi2[tid];

  // ---- last-block tail reduce (r14-validated visibility protocol) --------
  __threadfence();                     // release: partials -> device scope
  if (tid == 0){
    uint32_t old = atomicAdd(&cnt[b], 1u);
    amlast = (old == (uint32_t)(GG - 1)) ? 1 : 0;
  }
  __syncthreads();
  if (!amlast) return;
  __threadfence();                     // acquire side
  #pragma unroll
  for (int j = 0; j < 4; ++j)
    dev_reduce_row(pnumb, ppi, lqf8, logpi_w, out, b, wave * 4 + j, lane, dofinal);
}

__global__ __launch_bounds__(256) void k_fill(float* __restrict__ out, float v){
  out[blockIdx.x * 256 + threadIdx.x] = v;
}

extern "C" void kernel_launch(void* const* d_in, const int* in_sizes, int n_in,
                              void* d_out, int out_size, void* d_ws, size_t ws_size,
                              hipStream_t stream){
  const float* x    = (const float*)d_in[0];
  const float* sl   = (const float*)d_in[1];
  const float* mix  = (const float*)d_in[2];
  float* out = (float*)d_out;
  char* ws = (char*)d_ws;

  const size_t SZ_PBF  = 33554432ull;              // 8*1024*8*64*8
  const size_t SZ_XBF  = 33554432ull;              // 8*512*16*64*8
  const size_t SZ_LQF  = 32768ull;
  const size_t SZ_INV  = (size_t)BN*NN*4;          // 524288
  const size_t SZ_LP   = 512ull;
  const size_t SZ_PNUM = (size_t)BN*GG*KK*DD*2;    // 4 MB (bf16)
  const size_t SZ_PPI  = (size_t)BN*GG*KK*4;       // 32768
  const size_t SZ_CNT  = (size_t)NITER*BN*4;       // per-iter counters
  size_t need = SZ_PBF + SZ_XBF + SZ_LQF + SZ_INV + SZ_LP + SZ_PNUM + SZ_PPI + SZ_CNT;

  if (ws_size < need){
    k_fill<<<(BN*KK*DD)/256, 256, 0, stream>>>(out, -9.0f);   // diag
    return;
  }
  size_t o = 0;
  uint2*    pbf8  = (uint2*)(ws + o);     o += SZ_PBF;
  uint2*    xbf8  = (uint2*)(ws + o);     o += SZ_XBF;
  uint8_t*  lqf8  = (uint8_t*)(ws + o);   o += SZ_LQF;
  float*    invs  = (float*)(ws + o);     o += SZ_INV;
  float*    logpi = (float*)(ws + o);     o += SZ_LP;
  uint16_t* pnumb = (uint16_t*)(ws + o);  o += SZ_PNUM;
  float*    ppi   = (float*)(ws + o);     o += SZ_PPI;
  uint32_t* cnt   = (uint32_t*)(ws + o);

  hipMemsetAsync(cnt, 0, SZ_CNT, stream);          // deterministic counters
  k_prep6<<<dim3(512 / TPB, BN), 256, 0, stream>>>(x, pbf8, xbf8, invs);
  k_init6<<<(BN*KK)/4, 256, 0, stream>>>(sl, mix, lqf8, logpi);
  for (int it = 0; it < NITER; ++it){
    k_em7<<<dim3(GG, BN), 256, 0, stream>>>(pbf8, xbf8, (const uint2*)lqf8,
                                            logpi, invs, pnumb, ppi,
                                            lqf8, logpi, out,
                                            cnt + (size_t)it * BN,
                                            (it == NITER - 1) ? 1 : 0);
  }
}

// Round 18
// 159.173 us; speedup vs baseline: 3.1314x; 3.1314x over previous
//
#include <hip/hip_runtime.h>
#include <cstdint>
#include <cstddef>

#define BN 8
#define NN 16384
#define DD 256
#define KK 16
#define NITER 5
#define EPSV 1e-8f
#define LOG256 5.545177444479562f
#define PSTR 260   // LDS row stride (words); 1040 B, 16B-aligned
#define TPB 8      // S-tiles per prep block
#define GG 64      // split-N partial count per batch (512 blocks -> 2/CU)

typedef float f32x4 __attribute__((ext_vector_type(4)));
typedef long  i64v;

__device__ __forceinline__ float frcp(float x){ return __builtin_amdgcn_rcpf(x); }
__device__ __forceinline__ float wmax(float v){
  #pragma unroll
  for (int m = 32; m >= 1; m >>= 1) v = fmaxf(v, __shfl_xor(v, m, 64));
  return v;
}
__device__ __forceinline__ float wsum(float v){
  #pragma unroll
  for (int m = 32; m >= 1; m >>= 1) v += __shfl_xor(v, m, 64);
  return v;
}
__device__ __forceinline__ uint32_t pk4_fp8(float a, float b, float c, float d){
  int w = __builtin_amdgcn_cvt_pk_fp8_f32(a, b, 0, false);
  w = __builtin_amdgcn_cvt_pk_fp8_f32(c, d, w, true);
  return (uint32_t)w;
}
__device__ __forceinline__ uint32_t f2bf(float f){
  uint32_t u = __float_as_uint(f);
  return (u + 0x7fffu + ((u >> 16) & 1u)) >> 16;
}
__device__ __forceinline__ uint32_t pk2bf(float a, float b){
  return f2bf(a) | (f2bf(b) << 16);
}
__device__ __forceinline__ float bf2f(uint32_t h){ return __uint_as_float(h << 16); }

// ---- prep: single-buffer, 4 blocks/CU (r17-correctness-verified) ----------
// pbf8/xbf8/invs layouts identical to r12-verified kernels.
__global__ __launch_bounds__(256, 4) void k_prep6(const float* __restrict__ x,
                                                  uint2* __restrict__ pbf8,
                                                  uint2* __restrict__ xbf8,
                                                  float* __restrict__ invs){
  __shared__ float xs[32 * PSTR];                  // 33.3 KB single buffer
  const int b = blockIdx.y;
  const int Sbase = blockIdx.x * TPB;
  const int tid = threadIdx.x;
  const int wave = tid >> 6, lane = tid & 63;
  const float* xb = x + (size_t)b * NN * DD;

  for (int it = 0; it < TPB; ++it){
    const int S = Sbase + it;
    #pragma unroll
    for (int r = 0; r < 8; ++r){
      int row = wave * 8 + r;
      const float* gp = xb + ((size_t)S * 32 + row) * DD + lane * 4;
      float* lp = &xs[row * PSTR];
      __builtin_amdgcn_global_load_lds(
          (const __attribute__((address_space(1))) unsigned int*)gp,
          (__attribute__((address_space(3))) unsigned int*)lp, 16, 0, 0);
    }
    asm volatile("s_waitcnt vmcnt(0)" ::: "memory");
    __builtin_amdgcn_sched_barrier(0);
    __syncthreads();                               // xs ready (all waves)

    // ---- row sums --------------------------------------------------------
    {
      int row = 8 * wave + (lane & 7);
      const float* pr = &xs[row * PSTR + (lane >> 3) * 32];
      float a = 0.f;
      #pragma unroll
      for (int i = 0; i < 8; ++i){
        float4 v = *(const float4*)&pr[4 * i];
        a += __expf(v.x) + __expf(v.y) + __expf(v.z) + __expf(v.w);
      }
      a += __shfl_xor(a, 8, 64);
      a += __shfl_xor(a, 16, 64);
      a += __shfl_xor(a, 32, 64);
      if (lane < 8) invs[(size_t)b * NN + S * 32 + 8 * wave + lane] = frcp(a);
    }
    // ---- pbf pack: 4 (c,s) tasks per wave --------------------------------
    #pragma unroll
    for (int i = 0; i < 4; ++i){
      int p = wave * 4 + i; int c = p >> 3, s = p & 7;
      int rho = lane & 15;
      int n = 8 * (rho >> 2) + 4 * c + (rho & 3);
      int d = 32 * s + 8 * (lane >> 4);
      float4 v0 = *(const float4*)&xs[n * PSTR + d];
      float4 v1 = *(const float4*)&xs[n * PSTR + d + 4];
      uint2 o;
      o.x = pk4_fp8(__expf(v0.x), __expf(v0.y), __expf(v0.z), __expf(v0.w));
      o.y = pk4_fp8(__expf(v1.x), __expf(v1.y), __expf(v1.z), __expf(v1.w));
      pbf8[(((size_t)b * 1024 + (size_t)S * 2 + c) * 8 + s) * 64 + lane] = o;
    }
    // ---- xbf pack: 4 dt tasks per wave -----------------------------------
    #pragma unroll
    for (int i = 0; i < 4; ++i){
      int dt = wave * 4 + i;
      int col = dt * 16 + (lane & 15);
      int g2 = lane >> 4;
      float v[8];
      #pragma unroll
      for (int j = 0; j < 8; ++j) v[j] = xs[(8 * g2 + j) * PSTR + col];
      uint2 o;
      o.x = pk4_fp8(v[0], v[1], v[2], v[3]);
      o.y = pk4_fp8(v[4], v[5], v[6], v[7]);
      xbf8[(((size_t)b * 512 + S) * 16 + dt) * 64 + lane] = o;
    }
    __syncthreads();                               // done reading xs
  }
}

// ---- init: lq residual fp8 B-frags + logpi (r12-verified) -----------------
__global__ __launch_bounds__(256) void k_init6(const float* __restrict__ slot_logits,
                                               const float* __restrict__ mix,
                                               uint8_t* __restrict__ lqf8,
                                               float* __restrict__ logpi){
  int w    = blockIdx.x * 4 + (threadIdx.x >> 6);   // b*K + k
  int lane = threadIdx.x & 63;
  int b = w >> 4, k = w & 15;
  const float4* sl = (const float4*)(slot_logits + (size_t)k * DD);
  float4 t = sl[lane];
  float m = wmax(fmaxf(fmaxf(t.x, t.y), fmaxf(t.z, t.w)));
  float s = wsum(__expf(t.x-m) + __expf(t.y-m) + __expf(t.z-m) + __expf(t.w-m));
  float L = m + __logf(s) - LOG256;
  int d0 = lane * 4;
  int ss = d0 >> 5;
  int l2 = (((d0 & 31) >> 3) << 4) + k;
  int jb = d0 & 7;
  uint32_t wv = pk4_fp8(t.x - L, t.y - L, t.z - L, t.w - L);
  *(uint32_t*)(lqf8 + ((((size_t)b * 8 + ss) * 64 + l2) * 8 + jb)) = wv;
  if (lane == 0) logpi[w] = __logf(mix[k] + EPSV);
}

// ---- fused EM iteration via fp8 MFMA; bf16 partials (r15-verified) --------
__global__ __launch_bounds__(256, 2) void k_em6(const uint2* __restrict__ pbf8,
                                                const uint2* __restrict__ xbf8,
                                                const uint2* __restrict__ lqf8,
                                                const float* __restrict__ logpi,
                                                const float* __restrict__ invs,
                                                uint16_t* __restrict__ pnumb,
                                                float* __restrict__ ppi){
  __shared__ float sred[KK * DD];
  __shared__ float spi2[16];
  const int b = blockIdx.y, g = blockIdx.x;          // g: 0..GG-1
  const int tid = threadIdx.x;
  const int wave = tid >> 6, lane = tid & 63;

  i64v lq8[8];
  {
    const uint2* p = lqf8 + (size_t)b * 8 * 64 + lane;
    #pragma unroll
    for (int s = 0; s < 8; ++s){ uint2 t = p[s * 64]; lq8[s] = *(i64v*)&t; }
  }
  const float lpik = logpi[b * KK + (lane & 15)];

  f32x4 acc[16];
  #pragma unroll
  for (int dt = 0; dt < 16; ++dt) acc[dt] = (f32x4){0.f, 0.f, 0.f, 0.f};
  float piacc = 0.f;

  const int S0 = (g * 4 + wave) * 2;                 // 2 supersteps per wave
  #pragma unroll
  for (int ssi = 0; ssi < 2; ++ssi){
    const int S = S0 + ssi;
    const uint2* pb = pbf8 + (((size_t)b * 1024 + (size_t)S * 2) * 8) * 64 + lane;
    const uint2* xr = xbf8 + (((size_t)b * 512 + S) * 16) * 64 + lane;

    uint2 pa[16];
    #pragma unroll
    for (int i = 0; i < 16; ++i) pa[i] = pb[(size_t)i * 64];   // [c*8+s]

    float ivs[8];
    {
      const float* ib = invs + (size_t)b * NN + S * 32 + 8 * (lane >> 4);
      #pragma unroll
      for (int j = 0; j < 8; ++j) ivs[j] = ib[j];
    }

    float ga[8];
    #pragma unroll
    for (int c = 0; c < 2; ++c){
      f32x4 lc = (f32x4){0.f, 0.f, 0.f, 0.f};
      #pragma unroll
      for (int s = 0; s < 8; ++s){
        i64v a = *(i64v*)&pa[c * 8 + s];
        lc = __builtin_amdgcn_mfma_f32_16x16x32_fp8_fp8(a, lq8[s], lc, 0, 0, 0);
      }
      #pragma unroll
      for (int r2 = 0; r2 < 4; ++r2){
        float lg = fmaf(lc[r2], ivs[c * 4 + r2], lpik);
        float mx = lg;
        #pragma unroll
        for (int m = 1; m <= 8; m <<= 1) mx = fmaxf(mx, __shfl_xor(mx, m, 64));
        float e = __expf(lg - mx);
        float s2 = e;
        #pragma unroll
        for (int m = 1; m <= 8; m <<= 1) s2 += __shfl_xor(s2, m, 64);
        ga[c * 4 + r2] = e * frcp(s2);
      }
    }
    // gamma -> fp8 A-frag; DEQUANTIZED gamma for pi (consistency)
    uint2 gp;
    gp.x = pk4_fp8(ga[0], ga[1], ga[2], ga[3]);
    gp.y = pk4_fp8(ga[4], ga[5], ga[6], ga[7]);
    piacc += __builtin_amdgcn_cvt_f32_fp8((int)gp.x, 0)
           + __builtin_amdgcn_cvt_f32_fp8((int)gp.x, 1)
           + __builtin_amdgcn_cvt_f32_fp8((int)gp.x, 2)
           + __builtin_amdgcn_cvt_f32_fp8((int)gp.x, 3)
           + __builtin_amdgcn_cvt_f32_fp8((int)gp.y, 0)
           + __builtin_amdgcn_cvt_f32_fp8((int)gp.y, 1)
           + __builtin_amdgcn_cvt_f32_fp8((int)gp.y, 2)
           + __builtin_amdgcn_cvt_f32_fp8((int)gp.y, 3);
    i64v gA = *(i64v*)&gp;
    #pragma unroll
    for (int dt = 0; dt < 16; ++dt){
      uint2 xv = xr[(size_t)dt * 64];
      acc[dt] = __builtin_amdgcn_mfma_f32_16x16x32_fp8_fp8(gA, *(i64v*)&xv,
                                                           acc[dt], 0, 0, 0);
    }
  }

  // epilogue: cross-wave reduce (verified structure)
  float pk = piacc;
  pk += __shfl_xor(pk, 16, 64);
  pk += __shfl_xor(pk, 32, 64);
  __syncthreads();
  if (wave == 0){
    #pragma unroll
    for (int dt = 0; dt < 16; ++dt)
      #pragma unroll
      for (int r2 = 0; r2 < 4; ++r2)
        sred[(4 * (lane >> 4) + r2) * DD + dt * 16 + (lane & 15)] = acc[dt][r2];
    if (lane < 16) spi2[lane] = pk;
  }
  __syncthreads();
  for (int w = 1; w < 4; ++w){
    if (wave == w){
      #pragma unroll
      for (int dt = 0; dt < 16; ++dt)
        #pragma unroll
        for (int r2 = 0; r2 < 4; ++r2)
          sred[(4 * (lane >> 4) + r2) * DD + dt * 16 + (lane & 15)] += acc[dt][r2];
      if (lane < 16) spi2[lane] += pk;
    }
    __syncthreads();
  }
  uint32_t* dst = (uint32_t*)(pnumb + (size_t)(b * GG + g) * KK * DD);
  #pragma unroll
  for (int j = 0; j < 8; ++j){
    float a = sred[tid * 2 + j * 512];
    float c = sred[tid * 2 + 1 + j * 512];
    dst[tid + j * 256] = pk2bf(a, c);
  }
  if (tid < 16) ppi[(size_t)(b * GG + g) * KK + tid] = spi2[tid];
}

// ---- threefry (VERIFIED) --------------------------------------------------
__device__ __forceinline__ uint32_t rotl32(uint32_t x, int r){ return (x << r) | (x >> (32 - r)); }
__device__ __forceinline__ void tf2x32(uint32_t k0, uint32_t k1, uint32_t c0, uint32_t c1,
                                       uint32_t& o0, uint32_t& o1){
  uint32_t ks0 = k0, ks1 = k1, ks2 = 0x1BD11BDAu ^ k0 ^ k1;
  uint32_t x0 = c0 + ks0, x1 = c1 + ks1;
  #define RND(r) { x0 += x1; x1 = rotl32(x1, r); x1 ^= x0; }
  RND(13) RND(15) RND(26) RND(6)   x0 += ks1; x1 += ks2 + 1u;
  RND(17) RND(29) RND(16) RND(24)  x0 += ks2; x1 += ks0 + 2u;
  RND(13) RND(15) RND(26) RND(6)   x0 += ks0; x1 += ks1 + 3u;
  RND(17) RND(29) RND(16) RND(24)  x0 += ks1; x1 += ks2 + 4u;
  RND(13) RND(15) RND(26) RND(6)   x0 += ks2; x1 += ks0 + 5u;
  #undef RND
  o0 = x0; o1 = x1;
}

// ---- reduce; dofinal: inline gumbel+softmax -> out (r16-verified fold) ----
__global__ __launch_bounds__(64) void k_reduce6(const uint16_t* __restrict__ pnumb,
    const float* __restrict__ ppi, uint8_t* __restrict__ lqf8,
    float* __restrict__ logpi, float* __restrict__ out, int dofinal){
  int w = blockIdx.x;              // b*K + k
  int lane = threadIdx.x;
  int b = w >> 4, k = w & 15;
  float4 sum = make_float4(0.f, 0.f, 0.f, 0.f);
  #pragma unroll 4
  for (int g = 0; g < GG; ++g){
    const uint2* p = (const uint2*)(pnumb +
        ((size_t)(b * GG + g) * KK + k) * DD + lane * 4);
    uint2 v = *p;
    sum.x += bf2f(v.x & 0xffffu); sum.y += bf2f(v.x >> 16);
    sum.z += bf2f(v.y & 0xffffu); sum.w += bf2f(v.y >> 16);
  }
  float ps = 0.f;
  for (int g = lane; g < GG; g += 64) ps += ppi[((size_t)b * GG + g) * KK + k];
  ps = wsum(ps);
  float inv = frcp(ps + EPSV);
  float4 th = make_float4(sum.x * inv, sum.y * inv, sum.z * inv, sum.w * inv);

  if (!dofinal){
    float m = wmax(fmaxf(fmaxf(th.x, th.y), fmaxf(th.z, th.w)));
    float s = wsum(__expf(th.x-m) + __expf(th.y-m) + __expf(th.z-m) + __expf(th.w-m));
    float L = m + __logf(s) - LOG256;
    int d0 = lane * 4;
    int ss = d0 >> 5;
    int l2 = (((d0 & 31) >> 3) << 4) + k;
    int jb = d0 & 7;
    uint32_t wv = pk4_fp8(th.x - L, th.y - L, th.z - L, th.w - L);
    *(uint32_t*)(lqf8 + ((((size_t)b * 8 + ss) * 64 + l2) * 8 + jb)) = wv;
    if (lane == 0) logpi[w] = __logf(ps * (1.0f / NN) + EPSV);
    return;
  }

  // dofinal: gumbel (threefry partitionable XOR-fold, VERIFIED) + softmax
  int i0 = w * DD + lane * 4;
  float gv[4];
  #pragma unroll
  for (int j = 0; j < 4; ++j){
    uint32_t i = (uint32_t)(i0 + j);
    uint32_t o0, o1;
    tf2x32(0u, 1u, 0u, i, o0, o1);
    uint32_t bits = o0 ^ o1;
    float f = __uint_as_float((bits >> 9) | 0x3f800000u) - 1.0f;
    const float TINY = 1.17549435e-38f;
    float u = fmaxf(f + TINY, TINY);
    gv[j] = -logf(-logf(u));
  }
  float4 y = make_float4(th.x + gv[0], th.y + gv[1], th.z + gv[2], th.w + gv[3]);
  float m = wmax(fmaxf(fmaxf(y.x, y.y), fmaxf(y.z, y.w)));
  float4 e = make_float4(__expf(y.x-m), __expf(y.y-m), __expf(y.z-m), __expf(y.w-m));
  float s = wsum(e.x + e.y + e.z + e.w);
  float invq = 1.0f / s;
  ((float4*)(out + (size_t)w * DD))[lane] =
      make_float4(e.x*invq, e.y*invq, e.z*invq, e.w*invq);
}

__global__ __launch_bounds__(256) void k_fill(float* __restrict__ out, float v){
  out[blockIdx.x * 256 + threadIdx.x] = v;
}

extern "C" void kernel_launch(void* const* d_in, const int* in_sizes, int n_in,
                              void* d_out, int out_size, void* d_ws, size_t ws_size,
                              hipStream_t stream){
  const float* x    = (const float*)d_in[0];
  const float* sl   = (const float*)d_in[1];
  const float* mix  = (const float*)d_in[2];
  float* out = (float*)d_out;
  char* ws = (char*)d_ws;

  const size_t SZ_PBF  = 33554432ull;              // 8*1024*8*64*8
  const size_t SZ_XBF  = 33554432ull;              // 8*512*16*64*8
  const size_t SZ_LQF  = 32768ull;
  const size_t SZ_INV  = (size_t)BN*NN*4;          // 524288
  const size_t SZ_LP   = 512ull;
  const size_t SZ_PNUM = (size_t)BN*GG*KK*DD*2;    // 4 MB (bf16, GG=64)
  const size_t SZ_PPI  = (size_t)BN*GG*KK*4;       // 32768
  size_t need = SZ_PBF + SZ_XBF + SZ_LQF + SZ_INV + SZ_LP + SZ_PNUM + SZ_PPI;

  if (ws_size < need){
    k_fill<<<(BN*KK*DD)/256, 256, 0, stream>>>(out, -9.0f);   // diag
    return;
  }
  size_t o = 0;
  uint2*    pbf8  = (uint2*)(ws + o);     o += SZ_PBF;
  uint2*    xbf8  = (uint2*)(ws + o);     o += SZ_XBF;
  uint8_t*  lqf8  = (uint8_t*)(ws + o);   o += SZ_LQF;
  float*    invs  = (float*)(ws + o);     o += SZ_INV;
  float*    logpi = (float*)(ws + o);     o += SZ_LP;
  uint16_t* pnumb = (uint16_t*)(ws + o);  o += SZ_PNUM;
  float*    ppi   = (float*)(ws + o);

  k_prep6<<<dim3(512 / TPB, BN), 256, 0, stream>>>(x, pbf8, xbf8, invs);
  k_init6<<<(BN*KK)/4, 256, 0, stream>>>(sl, mix, lqf8, logpi);
  for (int it = 0; it < NITER; ++it){
    k_em6<<<dim3(GG, BN), 256, 0, stream>>>(pbf8, xbf8, (const uint2*)lqf8,
                                            logpi, invs, pnumb, ppi);
    k_reduce6<<<BN*KK, 64, 0, stream>>>(pnumb, ppi, lqf8, logpi, out,
                                        (it == NITER - 1) ? 1 : 0);
  }
}

// Round 19
// 158.180 us; speedup vs baseline: 3.1511x; 1.0063x over previous
//
#include <hip/hip_runtime.h>
#include <cstdint>
#include <cstddef>

#define BN 8
#define NN 16384
#define DD 256
#define KK 16
#define NITER 5
#define EPSV 1e-8f
#define LOG256 5.545177444479562f
#define PSTR 260   // LDS row stride (words); 1040 B, 16B-aligned
#define TPB 4      // S-tiles per prep block (1024 blocks -> 4/CU)
#define GG 64      // split-N partial count per batch (512 blocks)

typedef float f32x4 __attribute__((ext_vector_type(4)));
typedef long  i64v;

__device__ __forceinline__ float frcp(float x){ return __builtin_amdgcn_rcpf(x); }
__device__ __forceinline__ float wmax(float v){
  #pragma unroll
  for (int m = 32; m >= 1; m >>= 1) v = fmaxf(v, __shfl_xor(v, m, 64));
  return v;
}
__device__ __forceinline__ float wsum(float v){
  #pragma unroll
  for (int m = 32; m >= 1; m >>= 1) v += __shfl_xor(v, m, 64);
  return v;
}
__device__ __forceinline__ uint32_t pk4_fp8(float a, float b, float c, float d){
  int w = __builtin_amdgcn_cvt_pk_fp8_f32(a, b, 0, false);
  w = __builtin_amdgcn_cvt_pk_fp8_f32(c, d, w, true);
  return (uint32_t)w;
}
__device__ __forceinline__ uint32_t f2bf(float f){
  uint32_t u = __float_as_uint(f);
  return (u + 0x7fffu + ((u >> 16) & 1u)) >> 16;
}
__device__ __forceinline__ uint32_t pk2bf(float a, float b){
  return f2bf(a) | (f2bf(b) << 16);
}
__device__ __forceinline__ float bf2f(uint32_t h){ return __uint_as_float(h << 16); }

// ---- prep: single-buffer, TPB=4 -> 1024 blocks, 4/CU (TLP latency hiding) -
// pbf8/xbf8/invs layouts identical to r12-verified kernels.
__global__ __launch_bounds__(256, 4) void k_prep6(const float* __restrict__ x,
                                                  uint2* __restrict__ pbf8,
                                                  uint2* __restrict__ xbf8,
                                                  float* __restrict__ invs){
  __shared__ float xs[32 * PSTR];                  // 33.3 KB single buffer
  const int b = blockIdx.y;
  const int Sbase = blockIdx.x * TPB;
  const int tid = threadIdx.x;
  const int wave = tid >> 6, lane = tid & 63;
  const float* xb = x + (size_t)b * NN * DD;

  for (int it = 0; it < TPB; ++it){
    const int S = Sbase + it;
    #pragma unroll
    for (int r = 0; r < 8; ++r){
      int row = wave * 8 + r;
      const float* gp = xb + ((size_t)S * 32 + row) * DD + lane * 4;
      float* lp = &xs[row * PSTR];
      __builtin_amdgcn_global_load_lds(
          (const __attribute__((address_space(1))) unsigned int*)gp,
          (__attribute__((address_space(3))) unsigned int*)lp, 16, 0, 0);
    }
    asm volatile("s_waitcnt vmcnt(0)" ::: "memory");
    __builtin_amdgcn_sched_barrier(0);
    __syncthreads();                               // xs ready (all waves)

    // ---- row sums --------------------------------------------------------
    {
      int row = 8 * wave + (lane & 7);
      const float* pr = &xs[row * PSTR + (lane >> 3) * 32];
      float a = 0.f;
      #pragma unroll
      for (int i = 0; i < 8; ++i){
        float4 v = *(const float4*)&pr[4 * i];
        a += __expf(v.x) + __expf(v.y) + __expf(v.z) + __expf(v.w);
      }
      a += __shfl_xor(a, 8, 64);
      a += __shfl_xor(a, 16, 64);
      a += __shfl_xor(a, 32, 64);
      if (lane < 8) invs[(size_t)b * NN + S * 32 + 8 * wave + lane] = frcp(a);
    }
    // ---- pbf pack: 4 (c,s) tasks per wave --------------------------------
    #pragma unroll
    for (int i = 0; i < 4; ++i){
      int p = wave * 4 + i; int c = p >> 3, s = p & 7;
      int rho = lane & 15;
      int n = 8 * (rho >> 2) + 4 * c + (rho & 3);
      int d = 32 * s + 8 * (lane >> 4);
      float4 v0 = *(const float4*)&xs[n * PSTR + d];
      float4 v1 = *(const float4*)&xs[n * PSTR + d + 4];
      uint2 o;
      o.x = pk4_fp8(__expf(v0.x), __expf(v0.y), __expf(v0.z), __expf(v0.w));
      o.y = pk4_fp8(__expf(v1.x), __expf(v1.y), __expf(v1.z), __expf(v1.w));
      pbf8[(((size_t)b * 1024 + (size_t)S * 2 + c) * 8 + s) * 64 + lane] = o;
    }
    // ---- xbf pack: 4 dt tasks per wave -----------------------------------
    #pragma unroll
    for (int i = 0; i < 4; ++i){
      int dt = wave * 4 + i;
      int col = dt * 16 + (lane & 15);
      int g2 = lane >> 4;
      float v[8];
      #pragma unroll
      for (int j = 0; j < 8; ++j) v[j] = xs[(8 * g2 + j) * PSTR + col];
      uint2 o;
      o.x = pk4_fp8(v[0], v[1], v[2], v[3]);
      o.y = pk4_fp8(v[4], v[5], v[6], v[7]);
      xbf8[(((size_t)b * 512 + S) * 16 + dt) * 64 + lane] = o;
    }
    __syncthreads();                               // done reading xs
  }
}

// ---- init: lq residual fp8 B-frags + logpi (r12-verified) -----------------
__global__ __launch_bounds__(256) void k_init6(const float* __restrict__ slot_logits,
                                               const float* __restrict__ mix,
                                               uint8_t* __restrict__ lqf8,
                                               float* __restrict__ logpi){
  int w    = blockIdx.x * 4 + (threadIdx.x >> 6);   // b*K + k
  int lane = threadIdx.x & 63;
  int b = w >> 4, k = w & 15;
  const float4* sl = (const float4*)(slot_logits + (size_t)k * DD);
  float4 t = sl[lane];
  float m = wmax(fmaxf(fmaxf(t.x, t.y), fmaxf(t.z, t.w)));
  float s = wsum(__expf(t.x-m) + __expf(t.y-m) + __expf(t.z-m) + __expf(t.w-m));
  float L = m + __logf(s) - LOG256;
  int d0 = lane * 4;
  int ss = d0 >> 5;
  int l2 = (((d0 & 31) >> 3) << 4) + k;
  int jb = d0 & 7;
  uint32_t wv = pk4_fp8(t.x - L, t.y - L, t.z - L, t.w - L);
  *(uint32_t*)(lqf8 + ((((size_t)b * 8 + ss) * 64 + l2) * 8 + jb)) = wv;
  if (lane == 0) logpi[w] = __logf(mix[k] + EPSV);
}

// ---- fused EM iteration via fp8 MFMA; bf16 partials (r15-verified math) ---
__global__ __launch_bounds__(256, 4) void k_em6(const uint2* __restrict__ pbf8,
                                                const uint2* __restrict__ xbf8,
                                                const uint2* __restrict__ lqf8,
                                                const float* __restrict__ logpi,
                                                const float* __restrict__ invs,
                                                uint16_t* __restrict__ pnumb,
                                                float* __restrict__ ppi){
  __shared__ float sred[KK * DD];
  __shared__ float spi2[16];
  const int b = blockIdx.y, g = blockIdx.x;          // g: 0..GG-1
  const int tid = threadIdx.x;
  const int wave = tid >> 6, lane = tid & 63;

  i64v lq8[8];
  {
    const uint2* p = lqf8 + (size_t)b * 8 * 64 + lane;
    #pragma unroll
    for (int s = 0; s < 8; ++s){ uint2 t = p[s * 64]; lq8[s] = *(i64v*)&t; }
  }
  const float lpik = logpi[b * KK + (lane & 15)];

  f32x4 acc[16];
  #pragma unroll
  for (int dt = 0; dt < 16; ++dt) acc[dt] = (f32x4){0.f, 0.f, 0.f, 0.f};
  float piacc = 0.f;

  const int S0 = (g * 4 + wave) * 2;                 // 2 supersteps per wave
  #pragma unroll
  for (int ssi = 0; ssi < 2; ++ssi){
    const int S = S0 + ssi;
    const uint2* pb = pbf8 + (((size_t)b * 1024 + (size_t)S * 2) * 8) * 64 + lane;
    const uint2* xr = xbf8 + (((size_t)b * 512 + S) * 16) * 64 + lane;

    uint2 pa[16];
    #pragma unroll
    for (int i = 0; i < 16; ++i) pa[i] = pb[(size_t)i * 64];   // [c*8+s]

    float ivs[8];
    {
      const float* ib = invs + (size_t)b * NN + S * 32 + 8 * (lane >> 4);
      #pragma unroll
      for (int j = 0; j < 8; ++j) ivs[j] = ib[j];
    }

    float ga[8];
    #pragma unroll
    for (int c = 0; c < 2; ++c){
      f32x4 lc = (f32x4){0.f, 0.f, 0.f, 0.f};
      #pragma unroll
      for (int s = 0; s < 8; ++s){
        i64v a = *(i64v*)&pa[c * 8 + s];
        lc = __builtin_amdgcn_mfma_f32_16x16x32_fp8_fp8(a, lq8[s], lc, 0, 0, 0);
      }
      #pragma unroll
      for (int r2 = 0; r2 < 4; ++r2){
        float lg = fmaf(lc[r2], ivs[c * 4 + r2], lpik);
        float mx = lg;
        #pragma unroll
        for (int m = 1; m <= 8; m <<= 1) mx = fmaxf(mx, __shfl_xor(mx, m, 64));
        float e = __expf(lg - mx);
        float s2 = e;
        #pragma unroll
        for (int m = 1; m <= 8; m <<= 1) s2 += __shfl_xor(s2, m, 64);
        ga[c * 4 + r2] = e * frcp(s2);
      }
    }
    // gamma -> fp8 A-frag; DEQUANTIZED gamma for pi (consistency)
    uint2 gp;
    gp.x = pk4_fp8(ga[0], ga[1], ga[2], ga[3]);
    gp.y = pk4_fp8(ga[4], ga[5], ga[6], ga[7]);
    piacc += __builtin_amdgcn_cvt_f32_fp8((int)gp.x, 0)
           + __builtin_amdgcn_cvt_f32_fp8((int)gp.x, 1)
           + __builtin_amdgcn_cvt_f32_fp8((int)gp.x, 2)
           + __builtin_amdgcn_cvt_f32_fp8((int)gp.x, 3)
           + __builtin_amdgcn_cvt_f32_fp8((int)gp.y, 0)
           + __builtin_amdgcn_cvt_f32_fp8((int)gp.y, 1)
           + __builtin_amdgcn_cvt_f32_fp8((int)gp.y, 2)
           + __builtin_amdgcn_cvt_f32_fp8((int)gp.y, 3);
    i64v gA = *(i64v*)&gp;
    #pragma unroll
    for (int dt = 0; dt < 16; ++dt){
      uint2 xv = xr[(size_t)dt * 64];
      acc[dt] = __builtin_amdgcn_mfma_f32_16x16x32_fp8_fp8(gA, *(i64v*)&xv,
                                                           acc[dt], 0, 0, 0);
    }
  }

  // epilogue: cross-wave reduce (verified structure)
  float pk = piacc;
  pk += __shfl_xor(pk, 16, 64);
  pk += __shfl_xor(pk, 32, 64);
  __syncthreads();
  if (wave == 0){
    #pragma unroll
    for (int dt = 0; dt < 16; ++dt)
      #pragma unroll
      for (int r2 = 0; r2 < 4; ++r2)
        sred[(4 * (lane >> 4) + r2) * DD + dt * 16 + (lane & 15)] = acc[dt][r2];
    if (lane < 16) spi2[lane] = pk;
  }
  __syncthreads();
  for (int w = 1; w < 4; ++w){
    if (wave == w){
      #pragma unroll
      for (int dt = 0; dt < 16; ++dt)
        #pragma unroll
        for (int r2 = 0; r2 < 4; ++r2)
          sred[(4 * (lane >> 4) + r2) * DD + dt * 16 + (lane & 15)] += acc[dt][r2];
      if (lane < 16) spi2[lane] += pk;
    }
    __syncthreads();
  }
  uint32_t* dst = (uint32_t*)(pnumb + (size_t)(b * GG + g) * KK * DD);
  #pragma unroll
  for (int j = 0; j < 8; ++j){
    float a = sred[tid * 2 + j * 512];
    float c = sred[tid * 2 + 1 + j * 512];
    dst[tid + j * 256] = pk2bf(a, c);
  }
  if (tid < 16) ppi[(size_t)(b * GG + g) * KK + tid] = spi2[tid];
}

// ---- threefry (VERIFIED) --------------------------------------------------
__device__ __forceinline__ uint32_t rotl32(uint32_t x, int r){ return (x << r) | (x >> (32 - r)); }
__device__ __forceinline__ void tf2x32(uint32_t k0, uint32_t k1, uint32_t c0, uint32_t c1,
                                       uint32_t& o0, uint32_t& o1){
  uint32_t ks0 = k0, ks1 = k1, ks2 = 0x1BD11BDAu ^ k0 ^ k1;
  uint32_t x0 = c0 + ks0, x1 = c1 + ks1;
  #define RND(r) { x0 += x1; x1 = rotl32(x1, r); x1 ^= x0; }
  RND(13) RND(15) RND(26) RND(6)   x0 += ks1; x1 += ks2 + 1u;
  RND(17) RND(29) RND(16) RND(24)  x0 += ks2; x1 += ks0 + 2u;
  RND(13) RND(15) RND(26) RND(6)   x0 += ks0; x1 += ks1 + 3u;
  RND(17) RND(29) RND(16) RND(24)  x0 += ks1; x1 += ks2 + 4u;
  RND(13) RND(15) RND(26) RND(6)   x0 += ks2; x1 += ks0 + 5u;
  #undef RND
  o0 = x0; o1 = x1;
}

// ---- reduce; dofinal: inline gumbel+softmax -> out (r16/r18-verified) -----
__global__ __launch_bounds__(64) void k_reduce6(const uint16_t* __restrict__ pnumb,
    const float* __restrict__ ppi, uint8_t* __restrict__ lqf8,
    float* __restrict__ logpi, float* __restrict__ out, int dofinal){
  int w = blockIdx.x;              // b*K + k
  int lane = threadIdx.x;
  int b = w >> 4, k = w & 15;
  float4 sum = make_float4(0.f, 0.f, 0.f, 0.f);
  #pragma unroll 4
  for (int g = 0; g < GG; ++g){
    const uint2* p = (const uint2*)(pnumb +
        ((size_t)(b * GG + g) * KK + k) * DD + lane * 4);
    uint2 v = *p;
    sum.x += bf2f(v.x & 0xffffu); sum.y += bf2f(v.x >> 16);
    sum.z += bf2f(v.y & 0xffffu); sum.w += bf2f(v.y >> 16);
  }
  float ps = 0.f;
  for (int g = lane; g < GG; g += 64) ps += ppi[((size_t)b * GG + g) * KK + k];
  ps = wsum(ps);
  float inv = frcp(ps + EPSV);
  float4 th = make_float4(sum.x * inv, sum.y * inv, sum.z * inv, sum.w * inv);

  if (!dofinal){
    float m = wmax(fmaxf(fmaxf(th.x, th.y), fmaxf(th.z, th.w)));
    float s = wsum(__expf(th.x-m) + __expf(th.y-m) + __expf(th.z-m) + __expf(th.w-m));
    float L = m + __logf(s) - LOG256;
    int d0 = lane * 4;
    int ss = d0 >> 5;
    int l2 = (((d0 & 31) >> 3) << 4) + k;
    int jb = d0 & 7;
    uint32_t wv = pk4_fp8(th.x - L, th.y - L, th.z - L, th.w - L);
    *(uint32_t*)(lqf8 + ((((size_t)b * 8 + ss) * 64 + l2) * 8 + jb)) = wv;
    if (lane == 0) logpi[w] = __logf(ps * (1.0f / NN) + EPSV);
    return;
  }

  // dofinal: gumbel (threefry partitionable XOR-fold, VERIFIED) + softmax
  int i0 = w * DD + lane * 4;
  float gv[4];
  #pragma unroll
  for (int j = 0; j < 4; ++j){
    uint32_t i = (uint32_t)(i0 + j);
    uint32_t o0, o1;
    tf2x32(0u, 1u, 0u, i, o0, o1);
    uint32_t bits = o0 ^ o1;
    float f = __uint_as_float((bits >> 9) | 0x3f800000u) - 1.0f;
    const float TINY = 1.17549435e-38f;
    float u = fmaxf(f + TINY, TINY);
    gv[j] = -logf(-logf(u));
  }
  float4 y = make_float4(th.x + gv[0], th.y + gv[1], th.z + gv[2], th.w + gv[3]);
  float m = wmax(fmaxf(fmaxf(y.x, y.y), fmaxf(y.z, y.w)));
  float4 e = make_float4(__expf(y.x-m), __expf(y.y-m), __expf(y.z-m), __expf(y.w-m));
  float s = wsum(e.x + e.y + e.z + e.w);
  float invq = 1.0f / s;
  ((float4*)(out + (size_t)w * DD))[lane] =
      make_float4(e.x*invq, e.y*invq, e.z*invq, e.w*invq);
}

__global__ __launch_bounds__(256) void k_fill(float* __restrict__ out, float v){
  out[blockIdx.x * 256 + threadIdx.x] = v;
}

extern "C" void kernel_launch(void* const* d_in, const int* in_sizes, int n_in,
                              void* d_out, int out_size, void* d_ws, size_t ws_size,
                              hipStream_t stream){
  const float* x    = (const float*)d_in[0];
  const float* sl   = (const float*)d_in[1];
  const float* mix  = (const float*)d_in[2];
  float* out = (float*)d_out;
  char* ws = (char*)d_ws;

  const size_t SZ_PBF  = 33554432ull;              // 8*1024*8*64*8
  const size_t SZ_XBF  = 33554432ull;              // 8*512*16*64*8
  const size_t SZ_LQF  = 32768ull;
  const size_t SZ_INV  = (size_t)BN*NN*4;          // 524288
  const size_t SZ_LP   = 512ull;
  const size_t SZ_PNUM = (size_t)BN*GG*KK*DD*2;    // 4 MB (bf16, GG=64)
  const size_t SZ_PPI  = (size_t)BN*GG*KK*4;       // 32768
  size_t need = SZ_PBF + SZ_XBF + SZ_LQF + SZ_INV + SZ_LP + SZ_PNUM + SZ_PPI;

  if (ws_size < need){
    k_fill<<<(BN*KK*DD)/256, 256, 0, stream>>>(out, -9.0f);   // diag
    return;
  }
  size_t o = 0;
  uint2*    pbf8  = (uint2*)(ws + o);     o += SZ_PBF;
  uint2*    xbf8  = (uint2*)(ws + o);     o += SZ_XBF;
  uint8_t*  lqf8  = (uint8_t*)(ws + o);   o += SZ_LQF;
  float*    invs  = (float*)(ws + o);     o += SZ_INV;
  float*    logpi = (float*)(ws + o);     o += SZ_LP;
  uint16_t* pnumb = (uint16_t*)(ws + o);  o += SZ_PNUM;
  float*    ppi   = (float*)(ws + o);

  k_prep6<<<dim3(512 / TPB, BN), 256, 0, stream>>>(x, pbf8, xbf8, invs);
  k_init6<<<(BN*KK)/4, 256, 0, stream>>>(sl, mix, lqf8, logpi);
  for (int it = 0; it < NITER; ++it){
    k_em6<<<dim3(GG, BN), 256, 0, stream>>>(pbf8, xbf8, (const uint2*)lqf8,
                                            logpi, invs, pnumb, ppi);
    k_reduce6<<<BN*KK, 64, 0, stream>>>(pnumb, ppi, lqf8, logpi, out,
                                        (it == NITER - 1) ? 1 : 0);
  }
}